// Round 15
// baseline (6086.452 us; speedup 1.0000x reference)
//
#include <hip/hip_runtime.h>
#include <math.h>

namespace {

constexpr int TPB  = 512;
constexpr int NB   = 256;   // batch
constexpr int NT   = 1000;  // time steps
constexpr int NX   = 64;    // state dim
constexpr int NS   = 4;     // control dim
constexpr int DIN  = 68;    // NX + NS
constexpr int HF   = 256;
constexpr int HG   = 128;
constexpr float DTC   = 0.01f;
constexpr float SIGMA = 0.1f;

constexpr int HPAD  = 288;  // padded h storage: idx + (idx>>5)*4
constexpr int CH    = 68;   // dW/out chunk row stride
constexpr int WG1P  = 84;   // s_wg1p row stride: 4x20-slot padded slices + pad
constexpr int WG2LD = 136;  // s_wg2t row stride (16B-aligned rows)

typedef float v2f __attribute__((ext_vector_type(2)));

__device__ __forceinline__ int pmap(int i){ return i + ((i>>5)<<2); }

template<int CTRL>
__device__ __forceinline__ float dpp_add(float x){
    int y = __builtin_amdgcn_update_dpp(0, __float_as_int(x), CTRL, 0xF, 0xF, true);
    return x + __int_as_float(y);
}
// sum over lanes t^1, t^2 — quad_perm DPP (VALU pipe)
__device__ __forceinline__ float quad_sum(float x){
    x = dpp_add<0xB1>(x);   // quad_perm [1,0,3,2] : xor 1
    x = dpp_add<0x4E>(x);   // quad_perm [2,3,0,1] : xor 2
    return x;
}
// oct group = lane bits {0,1,3}: + xor8 via row_ror:8 — all DPP
__device__ __forceinline__ float oct_sum(float x){
    x = quad_sum(x);
    x = dpp_add<0x128>(x);  // row_ror:8 : lane l <-> l^8 within 16-lane row
    return x;
}

__device__ __forceinline__ float tanh_fast(float x){
    float e = __expf(2.0f*x);
    float r = __builtin_amdgcn_rcpf(e + 1.0f);
    return __builtin_fmaf(-2.0f, r, 1.0f);
}
__device__ __forceinline__ float softplus_f(float x){
    return fmaxf(x,0.0f) + __logf(1.0f + __expf(-fabsf(x)));
}

__device__ __forceinline__ v2f pkfma(v2f a, v2f b, v2f c){
    return __builtin_elementwise_fma(a, b, c);   // v_pk_fma_f32: 2 FMA / issue
}

// One workgroup = one batch element for all 1000 steps. 12 barriers/step.
// r14 base (4.63ms, VALUBusy 76%, no spill): scalar weights + keepalive +
// merged-tanh + G1-in-phaseA.
// This round: pack ONLY Wf2 as k-pairs (one uniform 64-pair block) — r12/r13
// spilled with 100 pairs across 3 arrays; 64 pairs + scalar A/C should fit.
// Both pkfma operands are natural pairs (no broadcasts).
__global__ __launch_bounds__(TPB, 1) void sde_rk4_kernel(
    const float* __restrict__ gIn, const float* __restrict__ gNz,
    const float* __restrict__ Wf1, const float* __restrict__ bf1,
    const float* __restrict__ Wf2, const float* __restrict__ bf2,
    const float* __restrict__ Wf3, const float* __restrict__ bf3,
    const float* __restrict__ Wg1, const float* __restrict__ bg1,
    const float* __restrict__ Wg2, const float* __restrict__ bg2,
    float* __restrict__ gOut)
{
    const int b = blockIdx.x;
    const int t = threadIdx.x;

    __shared__ __align__(16) float s_z[72];        // [X(64), u(4), pad=0]
    __shared__ __align__(16) float s_h1[HPAD];
    __shared__ __align__(16) float s_h2[HPAD];
    __shared__ __align__(16) float s_hg[HG];
    __shared__ __align__(16) float s_uall[4008];   // u[step][4] (+pad)
    __shared__ __align__(16) float s_dwc[NX*CH];   // dW chunk [x][64]
    __shared__ __align__(16) float s_out[NX*CH];   // out buffer [x][64]
    __shared__ __align__(16) float s_wg1p[HG*WG1P];   // [c][4 slices x 20 pad]
    __shared__ __align__(16) float s_wg2t[NX*WG2LD];  // [c][k] transposed

    // ---- thread roles (identical to r14) ----
    const int q2 = t & 3;                                   // quad slice id
    const int s8 = (t & 3) | (((t >> 3) & 1) << 2);         // oct slice (bits t0,t1,t3)
    const int gA = t >> 2;          const int cA0 = 2*gA;   // L1 col group (128)
    const int k0A = 16*q2;          const int lenA = (q2==3)?20:16;
    const int gB = ((t>>2)&1) | ((t>>4)<<1);                // oct col group (64)
    const int cB0 = 4*gB;           const int k0B = 32*s8;  // L2
    const int cC  = gB;             const int k0C = 32*s8;  // L3
    const int k0H = 16*s8;                                  // G2 k-slice
    const int cG  = gA;                                     // G1 col
    const bool oct0  = (s8 == 0);
    const int rD = t>>3, j0D = (t&7)*8;                     // chunk roles

    // ---- F-weights -> registers (zero-padded, 200 floats) ----
    float wf1a[20], wf1b[20];
#pragma unroll
    for (int k=0;k<20;++k){
        float wa=0.f, wb=0.f;
        if (k < lenA){
            wa = Wf1[(k0A+k)*HF + cA0];
            wb = Wf1[(k0A+k)*HF + cA0 + 1];
        }
        wf1a[k]=wa; wf1b[k]=wb;
    }
    v2f wf2kp[16][4];              // [kpair][col j]: {W[2k][j], W[2k+1][j]}
#pragma unroll
    for (int kp=0;kp<16;++kp){
        const float4 w0 = *(const float4*)&Wf2[(size_t)(k0B+2*kp)*HF + cB0];
        const float4 w1 = *(const float4*)&Wf2[(size_t)(k0B+2*kp+1)*HF + cB0];
        wf2kp[kp][0] = (v2f){w0.x, w1.x};
        wf2kp[kp][1] = (v2f){w0.y, w1.y};
        wf2kp[kp][2] = (v2f){w0.z, w1.z};
        wf2kp[kp][3] = (v2f){w0.w, w1.w};
    }
    float wf3s[32];
#pragma unroll
    for (int k=0;k<32;++k) wf3s[k] = Wf3[(k0C+k)*NX + cC];

    const float2 bf1v = *(const float2*)&bf1[cA0];
    const float4 bf2v = *(const float4*)&bf2[cB0];
    const float bf3c = bf3[cC];
    const float bg1c = bg1[cG];
    const float bg2c = bg2[cC];

    // per-lane merged-tanh bias + write pointer (init-time selects only)
    float bf2sel = (s8&1) ? bf2v.y : bf2v.x;
    { const float tz = (s8&1) ? bf2v.w : bf2v.z; bf2sel = (s8&2) ? tz : bf2sel; }
    float* const pA_w = (q2==2) ? &s_hg[cG] : &s_h1[pmap(cA0) + (q2&1)];
    float* const pB_w = &s_h2[pmap(cB0) + (s8&3)];

    const float sq = sqrtf(DTC);
    const float* inB = gIn + (size_t)b*DIN*NT;
    const float* nzB = gNz + (size_t)b*NX*NT;
    float*      outB = gOut + (size_t)b*NX*NT;

    // ---- G-weights -> LDS; u sequence -> LDS; initial state ----
    // s_wg1p: [c][84], slice q at 20q..20q+19 holds Wg1[16q+r] (zero-padded)
    for (int i=t; i<HG*WG1P; i+=TPB){
        const int c = i/WG1P, j = i - c*WG1P;
        float v = 0.f;
        if (j < 80){
            const int q = j/20, r = j - q*20;
            if (r < ((q==3)?20:16)) v = Wg1[(16*q+r)*HG + c];
        }
        s_wg1p[i] = v;
    }
    for (int i=t;i<HG*NX;i+=TPB){
        const int k=i>>6, c=i&(NX-1);
        s_wg2t[c*WG2LD+k] = Wg2[i];
    }
    for (int i=t;i<NS*NT; i+=TPB) s_uall[i] = inB[(i&3)*NT + (i>>2)];
    if (t<8)            s_uall[NS*NT+t] = 0.f;
    if (t>=68 && t<72)  s_z[t] = 0.f;
    if (t<4)            s_z[64+t] = inB[t*NT];
    float X = inB[(size_t)(NS+cC)*NT];   // replicated across oct group
    float kacc = 0.f, gc = 0.f;
    if (oct0) s_z[cC] = X;
    __syncthreads();

    const float* const wgp = &s_wg1p[cG*WG1P + 20*q2];

    // ---------- phases ----------
    auto phaseA = [&](bool withG){
        float a0=0.f,a1=0.f,b0=0.f,b1=0.f,g0=0.f,g1=0.f;
#pragma unroll
        for (int q=0;q<5;++q){                 // weights zero-padded beyond lenA
            const float4 zv = *(const float4*)&s_z[k0A + 4*q];
            a0 = fmaf(zv.x, wf1a[4*q+0], a0);  b0 = fmaf(zv.x, wf1b[4*q+0], b0);
            a1 = fmaf(zv.y, wf1a[4*q+1], a1);  b1 = fmaf(zv.y, wf1b[4*q+1], b1);
            a0 = fmaf(zv.z, wf1a[4*q+2], a0);  b0 = fmaf(zv.z, wf1b[4*q+2], b0);
            a1 = fmaf(zv.w, wf1a[4*q+3], a1);  b1 = fmaf(zv.w, wf1b[4*q+3], b1);
            if (withG){
                const float4 wv = *(const float4*)&wgp[4*q];  // padded slice
                g0 = fmaf(zv.x, wv.x, g0);
                g1 = fmaf(zv.y, wv.y, g1);
                g0 = fmaf(zv.z, wv.z, g0);
                g1 = fmaf(zv.w, wv.w, g1);
            }
        }
        const float r0 = quad_sum(a0 + a1);
        const float r1 = quad_sum(b0 + b1);
        // merged tanh: one issue, per-lane input select + per-lane pointer
        float x = (q2==1) ? r1 + bf1v.y : r0 + bf1v.x;
        if (withG){
            const float gr = quad_sum(g0 + g1);
            x = (q2==2) ? gr + bg1c : x;
        }
        const float tv = tanh_fast(x);
        if (q2 < 3) *pA_w = tv;   // q2==2 lane: s_hg (garbage in ev1-3, unread)
        __syncthreads();
    };

    auto phaseB = [&](bool withG){
        v2f a0={0.f,0.f}, a1={0.f,0.f}, a2={0.f,0.f}, a3={0.f,0.f};
        const float* h1p = &s_h1[36*s8];       // pmap(32*s8 + j) = 36*s8 + j
#pragma unroll
        for (int q=0;q<8;++q){
            const float4 hv = *(const float4*)&h1p[4*q];
            const v2f h01 = (v2f){hv.x, hv.y};
            const v2f h23 = (v2f){hv.z, hv.w};
            a0 = pkfma(h01, wf2kp[2*q+0][0], a0);
            a1 = pkfma(h01, wf2kp[2*q+0][1], a1);
            a2 = pkfma(h01, wf2kp[2*q+0][2], a2);
            a3 = pkfma(h01, wf2kp[2*q+0][3], a3);
            a0 = pkfma(h23, wf2kp[2*q+1][0], a0);
            a1 = pkfma(h23, wf2kp[2*q+1][1], a1);
            a2 = pkfma(h23, wf2kp[2*q+1][2], a2);
            a3 = pkfma(h23, wf2kp[2*q+1][3], a3);
        }
        const float d0 = oct_sum(a0[0] + a0[1]);
        const float d1 = oct_sum(a1[0] + a1[1]);
        const float d2 = oct_sum(a2[0] + a2[1]);
        const float d3 = oct_sum(a3[0] + a3[1]);
        if (withG){
            float g0=0.f, g1=0.f;
            const float* wt = &s_wg2t[cC*WG2LD + k0H];
            const float* hp = &s_hg[k0H];
#pragma unroll
            for (int q=0;q<4;++q){
                const float4 wv = *(const float4*)&wt[4*q];
                const float4 hg = *(const float4*)&hp[4*q];
                g0 = fmaf(hg.x, wv.x, g0);  g1 = fmaf(hg.y, wv.y, g1);
                g0 = fmaf(hg.z, wv.z, g0);  g1 = fmaf(hg.w, wv.w, g1);
            }
            const float gq = oct_sum(g0 + g1);
            gc = SIGMA*softplus_f(gq + bg2c);  // replicated across oct
        }
        // merged tanh: select d[s8&3], one issue, masked scalar write
        float xb = (s8&1) ? d1 : d0;
        { const float yb = (s8&1) ? d3 : d2; xb = (s8&2) ? yb : xb; }
        const float tv = tanh_fast(xb + bf2sel);
        if (s8 < 4) *pB_w = tv;
        __syncthreads();
    };

    auto phaseC = [&](int ev, int st){
        float e0=0.f, e1=0.f;
        const float* h2p = &s_h2[36*s8];
#pragma unroll
        for (int q=0;q<8;++q){
            const float4 hv = *(const float4*)&h2p[4*q];
            e0 = fmaf(hv.x, wf3s[4*q+0], e0);
            e1 = fmaf(hv.y, wf3s[4*q+1], e1);
            e0 = fmaf(hv.z, wf3s[4*q+2], e0);
            e1 = fmaf(hv.w, wf3s[4*q+3], e1);
        }
        const float kv = oct_sum(e0 + e1) + bf3c;      // replicated across oct
        if (ev==0)      kacc = kv;
        else if (ev==3) kacc += kv;
        else            kacc += 2.0f*kv;
        if (ev<3){
            if (oct0) s_z[cC] = fmaf((ev==2)?DTC:0.5f*DTC, kv, X);
        } else {
            const int jj = st & 63;
            const float dw = s_dwc[cC*CH + jj];        // broadcast within oct
            X = X + (DTC/6.0f)*kacc + gc*dw;           // replicated update
            if (oct0){
                s_z[cC] = X;
                s_out[cC*CH + jj] = X;
                if (cC < NS) s_z[64+cC] = s_uall[(st+1)*4 + cC];
            }
        }
        __syncthreads();
    };

    // ---------- main loop ----------
#pragma unroll 1
    for (int st=0; st<NT; ++st){
        // KEEPALIVE: opaquely redefine every F-weight register each step.
        // No instructions emitted; forbids sinking the weight loads back into
        // the loop (the r10 L2-refetch wall; removing this cost 2.8 ms).
#pragma unroll
        for (int k=0;k<20;++k)
            asm volatile("" : "+v"(wf1a[k]), "+v"(wf1b[k]));
#pragma unroll
        for (int kp=0;kp<16;++kp)
            asm volatile("" : "+v"(wf2kp[kp][0]), "+v"(wf2kp[kp][1]),
                              "+v"(wf2kp[kp][2]), "+v"(wf2kp[kp][3]));
#pragma unroll
        for (int k=0;k<32;++k)
            asm volatile("" : "+v"(wf3s[k]));

        if ((st & 63) == 0){
            if (st + 64 <= NT){
                const float4 v0 = *(const float4*)&nzB[(size_t)rD*NT + st + j0D];
                const float4 v1 = *(const float4*)&nzB[(size_t)rD*NT + st + j0D + 4];
                float* d = &s_dwc[rD*CH + j0D];
                d[0]=v0.x*sq; d[1]=v0.y*sq; d[2]=v0.z*sq; d[3]=v0.w*sq;
                d[4]=v1.x*sq; d[5]=v1.y*sq; d[6]=v1.z*sq; d[7]=v1.w*sq;
            } else {
#pragma unroll
                for (int e=0;e<8;++e){
                    const int j = j0D + e;
                    const float v = (st + j < NT) ? nzB[(size_t)rD*NT + st + j] : 0.f;
                    s_dwc[rD*CH + j] = v*sq;
                }
            }
        }

        phaseA(true);  phaseB(true);  phaseC(0, st);
#pragma unroll
        for (int ev=1; ev<4; ++ev){
            phaseA(false); phaseB(false); phaseC(ev, st);
        }

        const int jj = st & 63;
        if (jj == 63 || st == NT-1){
            const int st0 = st & ~63;
            const int cnt = st - st0 + 1;
            if (cnt == 64){
                const float4 w0 = *(const float4*)&s_out[rD*CH + j0D];
                const float4 w1 = *(const float4*)&s_out[rD*CH + j0D + 4];
                *(float4*)&outB[(size_t)rD*NT + st0 + j0D]     = w0;
                *(float4*)&outB[(size_t)rD*NT + st0 + j0D + 4] = w1;
            } else {
#pragma unroll
                for (int e=0;e<8;++e){
                    const int j = j0D + e;
                    if (j < cnt) outB[(size_t)rD*NT + st0 + j] = s_out[rD*CH + j];
                }
            }
        }
    }
}

} // namespace

extern "C" void kernel_launch(void* const* d_in, const int* in_sizes, int n_in,
                              void* d_out, int out_size, void* d_ws, size_t ws_size,
                              hipStream_t stream)
{
    const float* Inputs = (const float*)d_in[0];
    const float* noise  = (const float*)d_in[1];
    // d_in[2] = t0 (unused)
    const float* Wf1 = (const float*)d_in[3];
    const float* bf1 = (const float*)d_in[4];
    const float* Wf2 = (const float*)d_in[5];
    const float* bf2 = (const float*)d_in[6];
    const float* Wf3 = (const float*)d_in[7];
    const float* bf3 = (const float*)d_in[8];
    const float* Wg1 = (const float*)d_in[9];
    const float* bg1 = (const float*)d_in[10];
    const float* Wg2 = (const float*)d_in[11];
    const float* bg2 = (const float*)d_in[12];
    float* out = (float*)d_out;

    sde_rk4_kernel<<<dim3(NB), dim3(TPB), 0, stream>>>(
        Inputs, noise, Wf1, bf1, Wf2, bf2, Wf3, bf3, Wg1, bg1, Wg2, bg2, out);
}

// Round 16
// 4348.344 us; speedup vs baseline: 1.3997x; 1.3997x over previous
//
#include <hip/hip_runtime.h>
#include <math.h>

namespace {

constexpr int TPB  = 512;
constexpr int NB   = 256;   // batch
constexpr int NT   = 1000;  // time steps
constexpr int NX   = 64;    // state dim
constexpr int NS   = 4;     // control dim
constexpr int DIN  = 68;    // NX + NS
constexpr int HF   = 256;
constexpr int HG   = 128;
constexpr float DTC   = 0.01f;
constexpr float SIGMA = 0.1f;

constexpr int HPAD  = 288;  // padded h storage: idx + (idx>>5)*4
constexpr int CH    = 68;   // dW/out chunk row stride
constexpr int WG1P  = 84;   // s_wg1p row stride: 4x20-slot padded slices + pad
constexpr int WG2LD = 136;  // s_wg2t row stride (16B-aligned rows)

__device__ __forceinline__ int pmap(int i){ return i + ((i>>5)<<2); }

template<int CTRL>
__device__ __forceinline__ float dpp_add(float x){
    int y = __builtin_amdgcn_update_dpp(0, __float_as_int(x), CTRL, 0xF, 0xF, true);
    return x + __int_as_float(y);
}
template<int CTRL>
__device__ __forceinline__ float dpp_take(float x){   // partner's value only
    int y = __builtin_amdgcn_update_dpp(0, __float_as_int(x), CTRL, 0xF, 0xF, true);
    return __int_as_float(y);
}
// sum over lanes t^1, t^2 — quad_perm DPP (VALU pipe)
__device__ __forceinline__ float quad_sum(float x){
    x = dpp_add<0xB1>(x);   // quad_perm [1,0,3,2] : xor 1
    x = dpp_add<0x4E>(x);   // quad_perm [2,3,0,1] : xor 2
    return x;
}
// oct group = lane bits {0,1,3}: + xor8 via row_ror:8 — all DPP
__device__ __forceinline__ float oct_sum(float x){
    x = quad_sum(x);
    x = dpp_add<0x128>(x);  // row_ror:8 : lane l <-> l^8 within 16-lane row
    return x;
}

__device__ __forceinline__ float tanh_fast(float x){
    float e = __expf(2.0f*x);
    float r = __builtin_amdgcn_rcpf(e + 1.0f);
    return __builtin_fmaf(-2.0f, r, 1.0f);
}
__device__ __forceinline__ float softplus_f(float x){
    return fmaxf(x,0.0f) + __logf(1.0f + __expf(-fabsf(x)));
}

// One workgroup = one batch element for all 1000 steps. 12 barriers/step.
// r14 base (4.63ms, VALUBusy 76%, no spill): scalar register weights +
// per-step keepalive + merged-tanh + G1-in-phaseA.
// r12/r13/r15 lesson: ALL v2f weight-packing variants spill — scalar is final.
// This round: reduce-scatter reductions (select-then-exchange) in phaseB (4
// values/8 lanes: 24->14 instrs) and phaseA (2 values/4 lanes) — each lane
// ends holding exactly its merged-tanh input. Same butterfly stages & addition
// order as oct_sum/quad_sum -> bit-identical results.
__global__ __launch_bounds__(TPB, 1) void sde_rk4_kernel(
    const float* __restrict__ gIn, const float* __restrict__ gNz,
    const float* __restrict__ Wf1, const float* __restrict__ bf1,
    const float* __restrict__ Wf2, const float* __restrict__ bf2,
    const float* __restrict__ Wf3, const float* __restrict__ bf3,
    const float* __restrict__ Wg1, const float* __restrict__ bg1,
    const float* __restrict__ Wg2, const float* __restrict__ bg2,
    float* __restrict__ gOut)
{
    const int b = blockIdx.x;
    const int t = threadIdx.x;

    __shared__ __align__(16) float s_z[72];        // [X(64), u(4), pad=0]
    __shared__ __align__(16) float s_h1[HPAD];
    __shared__ __align__(16) float s_h2[HPAD];
    __shared__ __align__(16) float s_hg[HG];
    __shared__ __align__(16) float s_uall[4008];   // u[step][4] (+pad)
    __shared__ __align__(16) float s_dwc[NX*CH];   // dW chunk [x][64]
    __shared__ __align__(16) float s_out[NX*CH];   // out buffer [x][64]
    __shared__ __align__(16) float s_wg1p[HG*WG1P];   // [c][4 slices x 20 pad]
    __shared__ __align__(16) float s_wg2t[NX*WG2LD];  // [c][k] transposed

    // ---- thread roles (identical to r14) ----
    const int q2 = t & 3;                                   // quad slice id
    const int s8 = (t & 3) | (((t >> 3) & 1) << 2);         // oct slice (bits t0,t1,t3)
    const int gA = t >> 2;          const int cA0 = 2*gA;   // L1 col group (128)
    const int k0A = 16*q2;          const int lenA = (q2==3)?20:16;
    const int gB = ((t>>2)&1) | ((t>>4)<<1);                // oct col group (64)
    const int cB0 = 4*gB;           const int k0B = 32*s8;  // L2
    const int cC  = gB;             const int k0C = 32*s8;  // L3
    const int k0H = 16*s8;                                  // G2 k-slice
    const int cG  = gA;                                     // G1 col
    const bool oct0  = (s8 == 0);
    const bool lb0 = (t & 1);                               // lane bit selects
    const bool lb1 = (t & 2);
    const int rD = t>>3, j0D = (t&7)*8;                     // chunk roles

    // ---- F-weights -> scalar registers (zero-padded, 200 floats) ----
    float wf1a[20], wf1b[20];
#pragma unroll
    for (int k=0;k<20;++k){
        float wa=0.f, wb=0.f;
        if (k < lenA){
            wa = Wf1[(k0A+k)*HF + cA0];
            wb = Wf1[(k0A+k)*HF + cA0 + 1];
        }
        wf1a[k]=wa; wf1b[k]=wb;
    }
    float wf2s[32][4];
#pragma unroll
    for (int k=0;k<32;++k){
        const float4 wv = *(const float4*)&Wf2[(size_t)(k0B+k)*HF + cB0];
        wf2s[k][0]=wv.x; wf2s[k][1]=wv.y; wf2s[k][2]=wv.z; wf2s[k][3]=wv.w;
    }
    float wf3s[32];
#pragma unroll
    for (int k=0;k<32;++k) wf3s[k] = Wf3[(k0C+k)*NX + cC];

    const float2 bf1v = *(const float2*)&bf1[cA0];
    const float4 bf2v = *(const float4*)&bf2[cB0];
    const float bf3c = bf3[cC];
    const float bg1c = bg1[cG];
    const float bg2c = bg2[cC];

    // per-lane merged-tanh bias + write pointers (init-time selects only)
    const float bf1sel = lb0 ? bf1v.y : bf1v.x;
    float bf2sel = lb0 ? bf2v.y : bf2v.x;
    { const float tz = lb0 ? bf2v.w : bf2v.z; bf2sel = lb1 ? tz : bf2sel; }
    float* const pA_w = (q2==2) ? &s_hg[cG] : &s_h1[pmap(cA0) + (q2&1)];
    float* const pB_w = &s_h2[pmap(cB0) + (s8&3)];

    const float sq = sqrtf(DTC);
    const float* inB = gIn + (size_t)b*DIN*NT;
    const float* nzB = gNz + (size_t)b*NX*NT;
    float*      outB = gOut + (size_t)b*NX*NT;

    // ---- G-weights -> LDS; u sequence -> LDS; initial state ----
    // s_wg1p: [c][84], slice q at 20q..20q+19 holds Wg1[16q+r] (zero-padded)
    for (int i=t; i<HG*WG1P; i+=TPB){
        const int c = i/WG1P, j = i - c*WG1P;
        float v = 0.f;
        if (j < 80){
            const int q = j/20, r = j - q*20;
            if (r < ((q==3)?20:16)) v = Wg1[(16*q+r)*HG + c];
        }
        s_wg1p[i] = v;
    }
    for (int i=t;i<HG*NX;i+=TPB){
        const int k=i>>6, c=i&(NX-1);
        s_wg2t[c*WG2LD+k] = Wg2[i];
    }
    for (int i=t;i<NS*NT; i+=TPB) s_uall[i] = inB[(i&3)*NT + (i>>2)];
    if (t<8)            s_uall[NS*NT+t] = 0.f;
    if (t>=68 && t<72)  s_z[t] = 0.f;
    if (t<4)            s_z[64+t] = inB[t*NT];
    float X = inB[(size_t)(NS+cC)*NT];   // replicated across oct group
    float kacc = 0.f, gc = 0.f;
    if (oct0) s_z[cC] = X;
    __syncthreads();

    const float* const wgp = &s_wg1p[cG*WG1P + 20*q2];

    // ---------- phases ----------
    auto phaseA = [&](bool withG){
        float a0=0.f,a1=0.f,b0a=0.f,b1a=0.f,g0=0.f,g1=0.f;
#pragma unroll
        for (int q=0;q<5;++q){                 // weights zero-padded beyond lenA
            const float4 zv = *(const float4*)&s_z[k0A + 4*q];
            a0 = fmaf(zv.x, wf1a[4*q+0], a0);  b0a = fmaf(zv.x, wf1b[4*q+0], b0a);
            a1 = fmaf(zv.y, wf1a[4*q+1], a1);  b1a = fmaf(zv.y, wf1b[4*q+1], b1a);
            a0 = fmaf(zv.z, wf1a[4*q+2], a0);  b0a = fmaf(zv.z, wf1b[4*q+2], b0a);
            a1 = fmaf(zv.w, wf1a[4*q+3], a1);  b1a = fmaf(zv.w, wf1b[4*q+3], b1a);
            if (withG){
                const float4 wv = *(const float4*)&wgp[4*q];  // padded slice
                g0 = fmaf(zv.x, wv.x, g0);
                g1 = fmaf(zv.y, wv.y, g1);
                g0 = fmaf(zv.z, wv.z, g0);
                g1 = fmaf(zv.w, wv.w, g1);
            }
        }
        // reduce-scatter 2 values over quad: lane ends with value idx (t&1)
        const float sa = a0 + a1;
        const float sb = b0a + b1a;
        float p = lb0 ? sb : sa;               // keep own value
        const float u = lb0 ? sa : sb;         // send other value
        p += dpp_take<0xB1>(u);                // + partner(l^1)'s kept-value part
        p = dpp_add<0x4E>(p);                  // + pair(l^2) partial
        float x = p + bf1sel;
        if (withG){
            const float gr = quad_sum(g0 + g1);
            x = (q2==2) ? gr + bg1c : x;
        }
        const float tv = tanh_fast(x);
        if (q2 < 3) *pA_w = tv;   // q2==2 lane: s_hg (garbage in ev1-3, unread)
        __syncthreads();
    };

    auto phaseB = [&](bool withG){
        float c0=0.f,c1=0.f,c2=0.f,c3=0.f;
        const float* h1p = &s_h1[36*s8];       // pmap(32*s8 + j) = 36*s8 + j
#pragma unroll
        for (int q=0;q<8;++q){
            const float4 hv = *(const float4*)&h1p[4*q];
            c0 = fmaf(hv.x, wf2s[4*q+0][0], c0);
            c1 = fmaf(hv.x, wf2s[4*q+0][1], c1);
            c2 = fmaf(hv.x, wf2s[4*q+0][2], c2);
            c3 = fmaf(hv.x, wf2s[4*q+0][3], c3);
            c0 = fmaf(hv.y, wf2s[4*q+1][0], c0);
            c1 = fmaf(hv.y, wf2s[4*q+1][1], c1);
            c2 = fmaf(hv.y, wf2s[4*q+1][2], c2);
            c3 = fmaf(hv.y, wf2s[4*q+1][3], c3);
            c0 = fmaf(hv.z, wf2s[4*q+2][0], c0);
            c1 = fmaf(hv.z, wf2s[4*q+2][1], c1);
            c2 = fmaf(hv.z, wf2s[4*q+2][2], c2);
            c3 = fmaf(hv.z, wf2s[4*q+2][3], c3);
            c0 = fmaf(hv.w, wf2s[4*q+3][0], c0);
            c1 = fmaf(hv.w, wf2s[4*q+3][1], c1);
            c2 = fmaf(hv.w, wf2s[4*q+3][2], c2);
            c3 = fmaf(hv.w, wf2s[4*q+3][3], c3);
        }
        // reduce-scatter 4 values over oct: lane ends with value idx (s8&3)
        // stage 1 (xor1, lane bit0)
        float p = lb0 ? c1 : c0;
        float q = lb0 ? c3 : c2;
        const float u = lb0 ? c0 : c1;
        const float v = lb0 ? c2 : c3;
        p += dpp_take<0xB1>(u);
        q += dpp_take<0xB1>(v);
        // stage 2 (xor2, lane bit1)
        float r = lb1 ? q : p;
        const float s = lb1 ? p : q;
        r += dpp_take<0x4E>(s);
        // stage 3 (xor8, oct bit2)
        r = dpp_add<0x128>(r);
        if (withG){
            float g0=0.f, g1=0.f;
            const float* wt = &s_wg2t[cC*WG2LD + k0H];
            const float* hp = &s_hg[k0H];
#pragma unroll
            for (int qq=0;qq<4;++qq){
                const float4 wv = *(const float4*)&wt[4*qq];
                const float4 hg = *(const float4*)&hp[4*qq];
                g0 = fmaf(hg.x, wv.x, g0);  g1 = fmaf(hg.y, wv.y, g1);
                g0 = fmaf(hg.z, wv.z, g0);  g1 = fmaf(hg.w, wv.w, g1);
            }
            const float gq = oct_sum(g0 + g1);
            gc = SIGMA*softplus_f(gq + bg2c);  // replicated across oct
        }
        const float tv = tanh_fast(r + bf2sel);
        if (s8 < 4) *pB_w = tv;
        __syncthreads();
    };

    auto phaseC = [&](int ev, int st){
        float e0=0.f, e1=0.f;
        const float* h2p = &s_h2[36*s8];
#pragma unroll
        for (int q=0;q<8;++q){
            const float4 hv = *(const float4*)&h2p[4*q];
            e0 = fmaf(hv.x, wf3s[4*q+0], e0);
            e1 = fmaf(hv.y, wf3s[4*q+1], e1);
            e0 = fmaf(hv.z, wf3s[4*q+2], e0);
            e1 = fmaf(hv.w, wf3s[4*q+3], e1);
        }
        const float kv = oct_sum(e0 + e1) + bf3c;      // replicated across oct
        if (ev==0)      kacc = kv;
        else if (ev==3) kacc += kv;
        else            kacc += 2.0f*kv;
        if (ev<3){
            if (oct0) s_z[cC] = fmaf((ev==2)?DTC:0.5f*DTC, kv, X);
        } else {
            const int jj = st & 63;
            const float dw = s_dwc[cC*CH + jj];        // broadcast within oct
            X = X + (DTC/6.0f)*kacc + gc*dw;           // replicated update
            if (oct0){
                s_z[cC] = X;
                s_out[cC*CH + jj] = X;
                if (cC < NS) s_z[64+cC] = s_uall[(st+1)*4 + cC];
            }
        }
        __syncthreads();
    };

    // ---------- main loop ----------
#pragma unroll 1
    for (int st=0; st<NT; ++st){
        // KEEPALIVE: opaquely redefine every F-weight register each step.
        // No instructions emitted; forbids sinking the weight loads back into
        // the loop (the r10 L2-refetch wall; removing this cost 2.8 ms).
#pragma unroll
        for (int k=0;k<20;++k)
            asm volatile("" : "+v"(wf1a[k]), "+v"(wf1b[k]));
#pragma unroll
        for (int k=0;k<32;++k)
            asm volatile("" : "+v"(wf2s[k][0]), "+v"(wf2s[k][1]),
                              "+v"(wf2s[k][2]), "+v"(wf2s[k][3]));
#pragma unroll
        for (int k=0;k<32;++k)
            asm volatile("" : "+v"(wf3s[k]));

        if ((st & 63) == 0){
            if (st + 64 <= NT){
                const float4 v0 = *(const float4*)&nzB[(size_t)rD*NT + st + j0D];
                const float4 v1 = *(const float4*)&nzB[(size_t)rD*NT + st + j0D + 4];
                float* d = &s_dwc[rD*CH + j0D];
                d[0]=v0.x*sq; d[1]=v0.y*sq; d[2]=v0.z*sq; d[3]=v0.w*sq;
                d[4]=v1.x*sq; d[5]=v1.y*sq; d[6]=v1.z*sq; d[7]=v1.w*sq;
            } else {
#pragma unroll
                for (int e=0;e<8;++e){
                    const int j = j0D + e;
                    const float v = (st + j < NT) ? nzB[(size_t)rD*NT + st + j] : 0.f;
                    s_dwc[rD*CH + j] = v*sq;
                }
            }
        }

        phaseA(true);  phaseB(true);  phaseC(0, st);
#pragma unroll
        for (int ev=1; ev<4; ++ev){
            phaseA(false); phaseB(false); phaseC(ev, st);
        }

        const int jj = st & 63;
        if (jj == 63 || st == NT-1){
            const int st0 = st & ~63;
            const int cnt = st - st0 + 1;
            if (cnt == 64){
                const float4 w0 = *(const float4*)&s_out[rD*CH + j0D];
                const float4 w1 = *(const float4*)&s_out[rD*CH + j0D + 4];
                *(float4*)&outB[(size_t)rD*NT + st0 + j0D]     = w0;
                *(float4*)&outB[(size_t)rD*NT + st0 + j0D + 4] = w1;
            } else {
#pragma unroll
                for (int e=0;e<8;++e){
                    const int j = j0D + e;
                    if (j < cnt) outB[(size_t)rD*NT + st0 + j] = s_out[rD*CH + j];
                }
            }
        }
    }
}

} // namespace

extern "C" void kernel_launch(void* const* d_in, const int* in_sizes, int n_in,
                              void* d_out, int out_size, void* d_ws, size_t ws_size,
                              hipStream_t stream)
{
    const float* Inputs = (const float*)d_in[0];
    const float* noise  = (const float*)d_in[1];
    // d_in[2] = t0 (unused)
    const float* Wf1 = (const float*)d_in[3];
    const float* bf1 = (const float*)d_in[4];
    const float* Wf2 = (const float*)d_in[5];
    const float* bf2 = (const float*)d_in[6];
    const float* Wf3 = (const float*)d_in[7];
    const float* bf3 = (const float*)d_in[8];
    const float* Wg1 = (const float*)d_in[9];
    const float* bg1 = (const float*)d_in[10];
    const float* Wg2 = (const float*)d_in[11];
    const float* bg2 = (const float*)d_in[12];
    float* out = (float*)d_out;

    sde_rk4_kernel<<<dim3(NB), dim3(TPB), 0, stream>>>(
        Inputs, noise, Wf1, bf1, Wf2, bf2, Wf3, bf3, Wg1, bg1, Wg2, bg2, out);
}

// Round 17
// 4297.255 us; speedup vs baseline: 1.4164x; 1.0119x over previous
//
#include <hip/hip_runtime.h>
#include <math.h>

namespace {

constexpr int TPB  = 512;
constexpr int NB   = 256;   // batch
constexpr int NT   = 1000;  // time steps
constexpr int NX   = 64;    // state dim
constexpr int NS   = 4;     // control dim
constexpr int DIN  = 68;    // NX + NS
constexpr int HF   = 256;
constexpr int HG   = 128;
constexpr float DTC   = 0.01f;
constexpr float SIGMA = 0.1f;

constexpr int HPAD  = 288;  // padded h storage: idx + (idx>>5)*4
constexpr int CH    = 68;   // dW/out chunk row stride
constexpr int WG1P  = 84;   // s_wg1p row stride: 4x20-slot padded slices + pad
constexpr int WG2LD = 136;  // s_wg2t row stride (16B-aligned rows)

__device__ __forceinline__ int pmap(int i){ return i + ((i>>5)<<2); }

template<int CTRL>
__device__ __forceinline__ float dpp_add(float x){
    int y = __builtin_amdgcn_update_dpp(0, __float_as_int(x), CTRL, 0xF, 0xF, true);
    return x + __int_as_float(y);
}
template<int CTRL>
__device__ __forceinline__ float dpp_take(float x){   // partner's value only
    int y = __builtin_amdgcn_update_dpp(0, __float_as_int(x), CTRL, 0xF, 0xF, true);
    return __int_as_float(y);
}
// sum over lanes t^1, t^2 — quad_perm DPP (VALU pipe)
__device__ __forceinline__ float quad_sum(float x){
    x = dpp_add<0xB1>(x);   // quad_perm [1,0,3,2] : xor 1
    x = dpp_add<0x4E>(x);   // quad_perm [2,3,0,1] : xor 2
    return x;
}
// oct group = lane bits {0,1,3}: + xor8 via row_ror:8 — all DPP
__device__ __forceinline__ float oct_sum(float x){
    x = quad_sum(x);
    x = dpp_add<0x128>(x);  // row_ror:8 : lane l <-> l^8 within 16-lane row
    return x;
}

__device__ __forceinline__ float tanh_fast(float x){
    float e = __expf(2.0f*x);
    float r = __builtin_amdgcn_rcpf(e + 1.0f);
    return __builtin_fmaf(-2.0f, r, 1.0f);
}
__device__ __forceinline__ float softplus_f(float x){
    return fmaxf(x,0.0f) + __logf(1.0f + __expf(-fabsf(x)));
}

// One workgroup = one batch element for all 1000 steps. 12 barriers/step.
// r16 base (4.35ms, VALUBusy 77.5%): scalar register weights + keepalive +
// merged-tanh + G1-in-phaseA + reduce-scatter reductions.
// This round: keepalive HOISTED out of the loop (pre-loop volatile asm makes
// load-sinking equally illegal — the loop consumes opaque asm outputs) +
// a 1/64-step conditional keepalive as a liveness pin. Tests whether the
// per-step 200-operand tied-asm was generating hidden v_mov churn (the ~2x
// gap between source-level issue count and measured VALUBusy cycles).
__global__ __launch_bounds__(TPB, 1) void sde_rk4_kernel(
    const float* __restrict__ gIn, const float* __restrict__ gNz,
    const float* __restrict__ Wf1, const float* __restrict__ bf1,
    const float* __restrict__ Wf2, const float* __restrict__ bf2,
    const float* __restrict__ Wf3, const float* __restrict__ bf3,
    const float* __restrict__ Wg1, const float* __restrict__ bg1,
    const float* __restrict__ Wg2, const float* __restrict__ bg2,
    float* __restrict__ gOut)
{
    const int b = blockIdx.x;
    const int t = threadIdx.x;

    __shared__ __align__(16) float s_z[72];        // [X(64), u(4), pad=0]
    __shared__ __align__(16) float s_h1[HPAD];
    __shared__ __align__(16) float s_h2[HPAD];
    __shared__ __align__(16) float s_hg[HG];
    __shared__ __align__(16) float s_uall[4008];   // u[step][4] (+pad)
    __shared__ __align__(16) float s_dwc[NX*CH];   // dW chunk [x][64]
    __shared__ __align__(16) float s_out[NX*CH];   // out buffer [x][64]
    __shared__ __align__(16) float s_wg1p[HG*WG1P];   // [c][4 slices x 20 pad]
    __shared__ __align__(16) float s_wg2t[NX*WG2LD];  // [c][k] transposed

    // ---- thread roles (identical to r16) ----
    const int q2 = t & 3;                                   // quad slice id
    const int s8 = (t & 3) | (((t >> 3) & 1) << 2);         // oct slice (bits t0,t1,t3)
    const int gA = t >> 2;          const int cA0 = 2*gA;   // L1 col group (128)
    const int k0A = 16*q2;          const int lenA = (q2==3)?20:16;
    const int gB = ((t>>2)&1) | ((t>>4)<<1);                // oct col group (64)
    const int cB0 = 4*gB;           const int k0B = 32*s8;  // L2
    const int cC  = gB;             const int k0C = 32*s8;  // L3
    const int k0H = 16*s8;                                  // G2 k-slice
    const int cG  = gA;                                     // G1 col
    const bool oct0  = (s8 == 0);
    const bool lb0 = (t & 1);                               // lane bit selects
    const bool lb1 = (t & 2);
    const int rD = t>>3, j0D = (t&7)*8;                     // chunk roles

    // ---- F-weights -> scalar registers (zero-padded, 200 floats) ----
    float wf1a[20], wf1b[20];
#pragma unroll
    for (int k=0;k<20;++k){
        float wa=0.f, wb=0.f;
        if (k < lenA){
            wa = Wf1[(k0A+k)*HF + cA0];
            wb = Wf1[(k0A+k)*HF + cA0 + 1];
        }
        wf1a[k]=wa; wf1b[k]=wb;
    }
    float wf2s[32][4];
#pragma unroll
    for (int k=0;k<32;++k){
        const float4 wv = *(const float4*)&Wf2[(size_t)(k0B+k)*HF + cB0];
        wf2s[k][0]=wv.x; wf2s[k][1]=wv.y; wf2s[k][2]=wv.z; wf2s[k][3]=wv.w;
    }
    float wf3s[32];
#pragma unroll
    for (int k=0;k<32;++k) wf3s[k] = Wf3[(k0C+k)*NX + cC];

    const float2 bf1v = *(const float2*)&bf1[cA0];
    const float4 bf2v = *(const float4*)&bf2[cB0];
    const float bf3c = bf3[cC];
    const float bg1c = bg1[cG];
    const float bg2c = bg2[cC];

    // per-lane merged-tanh bias + write pointers (init-time selects only)
    const float bf1sel = lb0 ? bf1v.y : bf1v.x;
    float bf2sel = lb0 ? bf2v.y : bf2v.x;
    { const float tz = lb0 ? bf2v.w : bf2v.z; bf2sel = lb1 ? tz : bf2sel; }
    float* const pA_w = (q2==2) ? &s_hg[cG] : &s_h1[pmap(cA0) + (q2&1)];
    float* const pB_w = &s_h2[pmap(cB0) + (s8&3)];

    const float sq = sqrtf(DTC);
    const float* inB = gIn + (size_t)b*DIN*NT;
    const float* nzB = gNz + (size_t)b*NX*NT;
    float*      outB = gOut + (size_t)b*NX*NT;

    // ---- G-weights -> LDS; u sequence -> LDS; initial state ----
    // s_wg1p: [c][84], slice q at 20q..20q+19 holds Wg1[16q+r] (zero-padded)
    for (int i=t; i<HG*WG1P; i+=TPB){
        const int c = i/WG1P, j = i - c*WG1P;
        float v = 0.f;
        if (j < 80){
            const int q = j/20, r = j - q*20;
            if (r < ((q==3)?20:16)) v = Wg1[(16*q+r)*HG + c];
        }
        s_wg1p[i] = v;
    }
    for (int i=t;i<HG*NX;i+=TPB){
        const int k=i>>6, c=i&(NX-1);
        s_wg2t[c*WG2LD+k] = Wg2[i];
    }
    for (int i=t;i<NS*NT; i+=TPB) s_uall[i] = inB[(i&3)*NT + (i>>2)];
    if (t<8)            s_uall[NS*NT+t] = 0.f;
    if (t>=68 && t<72)  s_z[t] = 0.f;
    if (t<4)            s_z[64+t] = inB[t*NT];
    float X = inB[(size_t)(NS+cC)*NT];   // replicated across oct group
    float kacc = 0.f, gc = 0.f;
    if (oct0) s_z[cC] = X;
    __syncthreads();

    const float* const wgp = &s_wg1p[cG*WG1P + 20*q2];

    // ---------- phases ----------
    auto phaseA = [&](bool withG){
        float a0=0.f,a1=0.f,b0a=0.f,b1a=0.f,g0=0.f,g1=0.f;
#pragma unroll
        for (int q=0;q<5;++q){                 // weights zero-padded beyond lenA
            const float4 zv = *(const float4*)&s_z[k0A + 4*q];
            a0 = fmaf(zv.x, wf1a[4*q+0], a0);  b0a = fmaf(zv.x, wf1b[4*q+0], b0a);
            a1 = fmaf(zv.y, wf1a[4*q+1], a1);  b1a = fmaf(zv.y, wf1b[4*q+1], b1a);
            a0 = fmaf(zv.z, wf1a[4*q+2], a0);  b0a = fmaf(zv.z, wf1b[4*q+2], b0a);
            a1 = fmaf(zv.w, wf1a[4*q+3], a1);  b1a = fmaf(zv.w, wf1b[4*q+3], b1a);
            if (withG){
                const float4 wv = *(const float4*)&wgp[4*q];  // padded slice
                g0 = fmaf(zv.x, wv.x, g0);
                g1 = fmaf(zv.y, wv.y, g1);
                g0 = fmaf(zv.z, wv.z, g0);
                g1 = fmaf(zv.w, wv.w, g1);
            }
        }
        // reduce-scatter 2 values over quad: lane ends with value idx (t&1)
        const float sa = a0 + a1;
        const float sb = b0a + b1a;
        float p = lb0 ? sb : sa;               // keep own value
        const float u = lb0 ? sa : sb;         // send other value
        p += dpp_take<0xB1>(u);                // + partner(l^1)'s kept-value part
        p = dpp_add<0x4E>(p);                  // + pair(l^2) partial
        float x = p + bf1sel;
        if (withG){
            const float gr = quad_sum(g0 + g1);
            x = (q2==2) ? gr + bg1c : x;
        }
        const float tv = tanh_fast(x);
        if (q2 < 3) *pA_w = tv;   // q2==2 lane: s_hg (garbage in ev1-3, unread)
        __syncthreads();
    };

    auto phaseB = [&](bool withG){
        float c0=0.f,c1=0.f,c2=0.f,c3=0.f;
        const float* h1p = &s_h1[36*s8];       // pmap(32*s8 + j) = 36*s8 + j
#pragma unroll
        for (int q=0;q<8;++q){
            const float4 hv = *(const float4*)&h1p[4*q];
            c0 = fmaf(hv.x, wf2s[4*q+0][0], c0);
            c1 = fmaf(hv.x, wf2s[4*q+0][1], c1);
            c2 = fmaf(hv.x, wf2s[4*q+0][2], c2);
            c3 = fmaf(hv.x, wf2s[4*q+0][3], c3);
            c0 = fmaf(hv.y, wf2s[4*q+1][0], c0);
            c1 = fmaf(hv.y, wf2s[4*q+1][1], c1);
            c2 = fmaf(hv.y, wf2s[4*q+1][2], c2);
            c3 = fmaf(hv.y, wf2s[4*q+1][3], c3);
            c0 = fmaf(hv.z, wf2s[4*q+2][0], c0);
            c1 = fmaf(hv.z, wf2s[4*q+2][1], c1);
            c2 = fmaf(hv.z, wf2s[4*q+2][2], c2);
            c3 = fmaf(hv.z, wf2s[4*q+2][3], c3);
            c0 = fmaf(hv.w, wf2s[4*q+3][0], c0);
            c1 = fmaf(hv.w, wf2s[4*q+3][1], c1);
            c2 = fmaf(hv.w, wf2s[4*q+3][2], c2);
            c3 = fmaf(hv.w, wf2s[4*q+3][3], c3);
        }
        // reduce-scatter 4 values over oct: lane ends with value idx (s8&3)
        // stage 1 (xor1, lane bit0)
        float p = lb0 ? c1 : c0;
        float q = lb0 ? c3 : c2;
        const float u = lb0 ? c0 : c1;
        const float v = lb0 ? c2 : c3;
        p += dpp_take<0xB1>(u);
        q += dpp_take<0xB1>(v);
        // stage 2 (xor2, lane bit1)
        float r = lb1 ? q : p;
        const float s = lb1 ? p : q;
        r += dpp_take<0x4E>(s);
        // stage 3 (xor8, oct bit2)
        r = dpp_add<0x128>(r);
        if (withG){
            float g0=0.f, g1=0.f;
            const float* wt = &s_wg2t[cC*WG2LD + k0H];
            const float* hp = &s_hg[k0H];
#pragma unroll
            for (int qq=0;qq<4;++qq){
                const float4 wv = *(const float4*)&wt[4*qq];
                const float4 hg = *(const float4*)&hp[4*qq];
                g0 = fmaf(hg.x, wv.x, g0);  g1 = fmaf(hg.y, wv.y, g1);
                g0 = fmaf(hg.z, wv.z, g0);  g1 = fmaf(hg.w, wv.w, g1);
            }
            const float gq = oct_sum(g0 + g1);
            gc = SIGMA*softplus_f(gq + bg2c);  // replicated across oct
        }
        const float tv = tanh_fast(r + bf2sel);
        if (s8 < 4) *pB_w = tv;
        __syncthreads();
    };

    auto phaseC = [&](int ev, int st){
        float e0=0.f, e1=0.f;
        const float* h2p = &s_h2[36*s8];
#pragma unroll
        for (int q=0;q<8;++q){
            const float4 hv = *(const float4*)&h2p[4*q];
            e0 = fmaf(hv.x, wf3s[4*q+0], e0);
            e1 = fmaf(hv.y, wf3s[4*q+1], e1);
            e0 = fmaf(hv.z, wf3s[4*q+2], e0);
            e1 = fmaf(hv.w, wf3s[4*q+3], e1);
        }
        const float kv = oct_sum(e0 + e1) + bf3c;      // replicated across oct
        if (ev==0)      kacc = kv;
        else if (ev==3) kacc += kv;
        else            kacc += 2.0f*kv;
        if (ev<3){
            if (oct0) s_z[cC] = fmaf((ev==2)?DTC:0.5f*DTC, kv, X);
        } else {
            const int jj = st & 63;
            const float dw = s_dwc[cC*CH + jj];        // broadcast within oct
            X = X + (DTC/6.0f)*kacc + gc*dw;           // replicated update
            if (oct0){
                s_z[cC] = X;
                s_out[cC*CH + jj] = X;
                if (cC < NS) s_z[64+cC] = s_uall[(st+1)*4 + cC];
            }
        }
        __syncthreads();
    };

    // ---- KEEPALIVE (pre-loop): opaquely redefine every F-weight register
    // ONCE before the loop. The loop then consumes asm outputs — sinking the
    // weight loads into the loop is illegal (can't rematerialize volatile
    // asm), same residency guarantee as r11's per-step form but with zero
    // per-iteration tied-operand churn.
#pragma unroll
    for (int k=0;k<20;++k)
        asm volatile("" : "+v"(wf1a[k]), "+v"(wf1b[k]));
#pragma unroll
    for (int k=0;k<32;++k)
        asm volatile("" : "+v"(wf2s[k][0]), "+v"(wf2s[k][1]),
                          "+v"(wf2s[k][2]), "+v"(wf2s[k][3]));
#pragma unroll
    for (int k=0;k<32;++k)
        asm volatile("" : "+v"(wf3s[k]));

    // ---------- main loop ----------
#pragma unroll 1
    for (int st=0; st<NT; ++st){
        if ((st & 63) == 0){
            // liveness pin: rare in-loop keepalive (1/64 steps) keeps the
            // allocator from considering cross-loop spill profitable.
#pragma unroll
            for (int k=0;k<20;++k)
                asm volatile("" : "+v"(wf1a[k]), "+v"(wf1b[k]));
#pragma unroll
            for (int k=0;k<32;++k)
                asm volatile("" : "+v"(wf2s[k][0]), "+v"(wf2s[k][1]),
                                  "+v"(wf2s[k][2]), "+v"(wf2s[k][3]));
#pragma unroll
            for (int k=0;k<32;++k)
                asm volatile("" : "+v"(wf3s[k]));

            if (st + 64 <= NT){
                const float4 v0 = *(const float4*)&nzB[(size_t)rD*NT + st + j0D];
                const float4 v1 = *(const float4*)&nzB[(size_t)rD*NT + st + j0D + 4];
                float* d = &s_dwc[rD*CH + j0D];
                d[0]=v0.x*sq; d[1]=v0.y*sq; d[2]=v0.z*sq; d[3]=v0.w*sq;
                d[4]=v1.x*sq; d[5]=v1.y*sq; d[6]=v1.z*sq; d[7]=v1.w*sq;
            } else {
#pragma unroll
                for (int e=0;e<8;++e){
                    const int j = j0D + e;
                    const float v = (st + j < NT) ? nzB[(size_t)rD*NT + st + j] : 0.f;
                    s_dwc[rD*CH + j] = v*sq;
                }
            }
        }

        phaseA(true);  phaseB(true);  phaseC(0, st);
#pragma unroll
        for (int ev=1; ev<4; ++ev){
            phaseA(false); phaseB(false); phaseC(ev, st);
        }

        const int jj = st & 63;
        if (jj == 63 || st == NT-1){
            const int st0 = st & ~63;
            const int cnt = st - st0 + 1;
            if (cnt == 64){
                const float4 w0 = *(const float4*)&s_out[rD*CH + j0D];
                const float4 w1 = *(const float4*)&s_out[rD*CH + j0D + 4];
                *(float4*)&outB[(size_t)rD*NT + st0 + j0D]     = w0;
                *(float4*)&outB[(size_t)rD*NT + st0 + j0D + 4] = w1;
            } else {
#pragma unroll
                for (int e=0;e<8;++e){
                    const int j = j0D + e;
                    if (j < cnt) outB[(size_t)rD*NT + st0 + j] = s_out[rD*CH + j];
                }
            }
        }
    }
}

} // namespace

extern "C" void kernel_launch(void* const* d_in, const int* in_sizes, int n_in,
                              void* d_out, int out_size, void* d_ws, size_t ws_size,
                              hipStream_t stream)
{
    const float* Inputs = (const float*)d_in[0];
    const float* noise  = (const float*)d_in[1];
    // d_in[2] = t0 (unused)
    const float* Wf1 = (const float*)d_in[3];
    const float* bf1 = (const float*)d_in[4];
    const float* Wf2 = (const float*)d_in[5];
    const float* bf2 = (const float*)d_in[6];
    const float* Wf3 = (const float*)d_in[7];
    const float* bf3 = (const float*)d_in[8];
    const float* Wg1 = (const float*)d_in[9];
    const float* bg1 = (const float*)d_in[10];
    const float* Wg2 = (const float*)d_in[11];
    const float* bg2 = (const float*)d_in[12];
    float* out = (float*)d_out;

    sde_rk4_kernel<<<dim3(NB), dim3(TPB), 0, stream>>>(
        Inputs, noise, Wf1, bf1, Wf2, bf2, Wf3, bf3, Wg1, bg1, Wg2, bg2, out);
}